// Round 6
// baseline (344.957 us; speedup 1.0000x reference)
//
#include <hip/hip_runtime.h>
#include <math.h>

#define LQ 2048
#define DM 1024
#define NH 16
#define DH 64
#define UU 38
#define NBH 64            // B*NH = 4*16
#define SCALE 0.125f      // 1/sqrt(64)

typedef _Float16 f16x8 __attribute__((ext_vector_type(8)));
typedef float f32x4 __attribute__((ext_vector_type(4)));
typedef float f32x2 __attribute__((ext_vector_type(2)));

#if __has_builtin(__builtin_amdgcn_exp2f)
#define EXP2F(x) __builtin_amdgcn_exp2f(x)
#else
#define EXP2F(x) exp2f(x)
#endif

// async global->LDS DMA, 16B per lane. LDS dest is wave-uniform base + lane*16.
#define GL2LDS16(gp, lp)                                           \
  __builtin_amdgcn_global_load_lds(                                \
      (const __attribute__((address_space(1))) void*)(gp),         \
      (__attribute__((address_space(3))) void*)(lp), 16, 0, 0)

// ---- workspace layout (bytes), total 40,700,928 (proven to fit in r8) ----
//   lt    : [2][64][2048][2] f64           [0, 4194304)
//   sel   : 64*38 int                       +9728
//   l3    : 64*38 f32  <- r14: LIVE again; written by topk2 (f64-accurate
//           softmax denominator of each selected row, from kl's l64 path)
//   mask  : [64][2048] s8                   +131072
//   lpart : (DELETED in r14 -- slot kept for layout stability)
//   ksp   : [64][32][8192] f16 @ 7146496    (33,554,432 B)
//   opart : r14: block (bh,ks) writes its 9,728-B partial into the FIRST
//           bytes of ITS OWN 32 KB ksp slice (offset (bh*32+ks*2)*16384).
//           Per-block self-alias only: written strictly after that block's
//           last ksp read (phase barrier) -- no cross-block hazard.
#define F_OFF_SEL   4194304
#define F_OFF_L3    4204032
#define F_OFF_MASK  4213760
#define F_OFF_LPART 4344832
#define F_OFF_KSP   7146496
#define F_NEED      40700928ull

// ---------------------------------------------------------------------------
// ksplit: one-time K fp32 -> fp16 hi/lo split with the conflict-free LDS
// image pre-baked (dim-block p stored at p^(k&7)). Unchanged (validated).
// ---------------------------------------------------------------------------
__global__ __launch_bounds__(256) void ksplit_kernel(const float* __restrict__ K,
                                                     _Float16* __restrict__ ksp) {
  int idx = blockIdx.x * 256 + threadIdx.x;   // 1,048,576 total
  int p = idx & 7;
  int k = (idx >> 3) & 63;
  int kc = (idx >> 9) & 31;
  int bh = idx >> 14;
  int b = bh >> 4, h = bh & 15;
  const float* src = K + ((size_t)(b * LQ + kc * 64 + k)) * DM + h * DH + (p ^ (k & 7)) * 8;
  float4 x0 = *(const float4*)src;
  float4 x1 = *(const float4*)(src + 4);
  f16x8 hi, lo;
#define KCV(i, xx) { float x_ = (xx); _Float16 hh = (_Float16)x_; hi[i] = hh; lo[i] = (_Float16)(x_ - (float)hh); }
  KCV(0, x0.x) KCV(1, x0.y) KCV(2, x0.z) KCV(3, x0.w)
  KCV(4, x1.x) KCV(5, x1.y) KCV(6, x1.z) KCV(7, x1.w)
#undef KCV
  _Float16* base = ksp + ((size_t)(bh * 32 + kc)) * 8192;
  *(f16x8*)(base + k * 64 + p * 8) = hi;
  *(f16x8*)(base + 4096 + k * 64 + p * 8) = lo;
}

// ---------------------------------------------------------------------------
// kl_mfma2: r12/r13 state, UNCHANGED (validated 127.5us; at structural floor).
// ---------------------------------------------------------------------------
__global__ __launch_bounds__(256) void kl_mfma2(const float* __restrict__ Q,
                                                const _Float16* __restrict__ ksp,
                                                double* __restrict__ lt) {
  int bh = blockIdx.x & 63;
  int qc = (blockIdx.x >> 6) & 15;
  int sp = blockIdx.x >> 10;
  int b = bh >> 4, h = bh & 15;
  int t = threadIdx.x;
  int lane = t & 63, w = t >> 6;
  int quad = lane >> 4, l15 = lane & 15;

  __shared__ __align__(16) _Float16 kbuf[8192];   // 16 KB = 2 x 8 KB dbuf

  f16x8 ahi[2][2], alo[2][2];
  {
    const float* qrow = Q + ((size_t)(b * LQ + qc * 128)) * DM + h * DH;
#pragma unroll
    for (int qt = 0; qt < 2; ++qt)
#pragma unroll
      for (int c = 0; c < 2; ++c) {
        const float* p = qrow + (size_t)(w * 32 + qt * 16 + l15) * DM + c * 32 + quad * 8;
        float4 x0 = *(const float4*)p;
        float4 x1 = *(const float4*)(p + 4);
        f16x8 hi, lo;
#define QCV(i, xx) { float x_ = (xx); _Float16 hh = (_Float16)x_; hi[i] = hh; lo[i] = (_Float16)(x_ - (float)hh); }
        QCV(0, x0.x) QCV(1, x0.y) QCV(2, x0.z) QCV(3, x0.w)
        QCV(4, x1.x) QCV(5, x1.y) QCV(6, x1.z) QCV(7, x1.w)
#undef QCV
        ahi[qt][c] = hi;
        alo[qt][c] = lo;
      }
  }

  int bsw0 = quad ^ (l15 & 7);
  int bsw1 = (quad + 4) ^ (l15 & 7);
  const float C1 = 0.18033688011112042f;  // SCALE * log2(e)

  double l64[2][4], t64[2][4];
#pragma unroll
  for (int qt = 0; qt < 2; ++qt)
#pragma unroll
    for (int r = 0; r < 4; ++r) { l64[qt][r] = 0.0; t64[qt][r] = 0.0; }

  const _Float16* khiA = kbuf;
  const _Float16* kloA = kbuf + 2048;
  const _Float16* khiB = kbuf + 4096;
  const _Float16* kloB = kbuf + 6144;

  const char* gp = (const char*)(ksp + ((size_t)(bh * 32 + sp * 16)) * 8192) + t * 16;
  char* ldsA = (char*)kbuf + w * 1024;          // wave-uniform dests
  char* ldsB = (char*)kbuf + 8192 + w * 1024;

#define KLSTEP(KHI, KLO)                                                        \
  _Pragma("unroll")                                                             \
  for (int kt = 0; kt < 2; ++kt) {                                              \
    int key = kt * 16 + l15;                                                    \
    f16x8 bhi0 = *(const f16x8*)((KHI) + key * 64 + bsw0 * 8);                  \
    f16x8 bhi1 = *(const f16x8*)((KHI) + key * 64 + bsw1 * 8);                  \
    f16x8 blo0 = *(const f16x8*)((KLO) + key * 64 + bsw0 * 8);                  \
    f16x8 blo1 = *(const f16x8*)((KLO) + key * 64 + bsw1 * 8);                  \
    _Pragma("unroll")                                                           \
    for (int qt = 0; qt < 2; ++qt) {                                            \
      f32x4 cacc = {0.f, 0.f, 0.f, 0.f};                                        \
      cacc = __builtin_amdgcn_mfma_f32_16x16x32_f16(alo[qt][0], bhi0, cacc, 0, 0, 0); \
      cacc = __builtin_amdgcn_mfma_f32_16x16x32_f16(alo[qt][1], bhi1, cacc, 0, 0, 0); \
      cacc = __builtin_amdgcn_mfma_f32_16x16x32_f16(ahi[qt][0], blo0, cacc, 0, 0, 0); \
      cacc = __builtin_amdgcn_mfma_f32_16x16x32_f16(ahi[qt][1], blo1, cacc, 0, 0, 0); \
      cacc = __builtin_amdgcn_mfma_f32_16x16x32_f16(ahi[qt][0], bhi0, cacc, 0, 0, 0); \
      cacc = __builtin_amdgcn_mfma_f32_16x16x32_f16(ahi[qt][1], bhi1, cacc, 0, 0, 0); \
      _Pragma("unroll")                                                         \
      for (int rp = 0; rp < 2; ++rp) {                                          \
        f32x2 rr = { cacc[2 * rp], cacc[2 * rp + 1] };                          \
        f32x2 sc = rr * C1;                    /* v_pk_mul_f32 */               \
        f32x2 e  = { EXP2F(sc[0]), EXP2F(sc[1]) };                              \
        l32[qt][rp] += e;                      /* v_pk_add_f32 */               \
        t32[qt][rp] += rr * e;                 /* v_pk_fma_f32 */               \
      }                                                                         \
    }                                                                           \
  }

  GL2LDS16(gp, ldsA);
  GL2LDS16(gp + 8192, ldsA + 4096);
  __syncthreads();

  for (int j = 0; j < 16; ++j) {
    GL2LDS16(gp + 4096, ldsB);
    GL2LDS16(gp + 12288, ldsB + 4096);

    f32x2 l32[2][2], t32[2][2];
#pragma unroll
    for (int qt = 0; qt < 2; ++qt)
#pragma unroll
      for (int rp = 0; rp < 2; ++rp) {
        l32[qt][rp] = (f32x2){0.f, 0.f};
        t32[qt][rp] = (f32x2){0.f, 0.f};
      }

    KLSTEP(khiA, kloA)
    __syncthreads();

    if (j < 15) {
      gp += 16384;
      GL2LDS16(gp, ldsA);
      GL2LDS16(gp + 8192, ldsA + 4096);
    }

    KLSTEP(khiB, kloB)

#pragma unroll
    for (int qt = 0; qt < 2; ++qt)
#pragma unroll
      for (int rp = 0; rp < 2; ++rp)
#pragma unroll
        for (int c = 0; c < 2; ++c) {
          l64[qt][rp * 2 + c] += (double)l32[qt][rp][c];
          t64[qt][rp * 2 + c] += (double)t32[qt][rp][c];
        }
    __syncthreads();
  }
#undef KLSTEP

#pragma unroll
  for (int qt = 0; qt < 2; ++qt)
#pragma unroll
    for (int r = 0; r < 4; ++r) {
      double lv = l64[qt][r], tv = t64[qt][r];
#pragma unroll
      for (int m = 1; m < 16; m <<= 1) {
        lv += __shfl_xor(lv, m);
        tv += __shfl_xor(tv, m);
      }
      if (l15 == 0) {
        int qg = qc * 128 + w * 32 + qt * 16 + quad * 4 + r;
        double* dst = lt + ((size_t)(sp * 64 + bh) * LQ + qg) * 2;
        dst[0] = lv;
        dst[1] = tv;
      }
    }
}

// ---------------------------------------------------------------------------
// topk2 r14: register top-3 scheme from r13 (validated), PLUS: the full-range
// softmax denominator l = p0[0]+p1[0] (f64, from kl's l64 path -- the exact
// same exp2(raw*C1) terms the attn path recomputes) is cached in LDS and the
// owner lane emits l3[bh][u] = l at selection time. attn normalization is
// thereby known BEFORE the attention kernel runs -- kills lpart/attn_pv2.
// ---------------------------------------------------------------------------
__global__ __launch_bounds__(64) void topk2(const double* __restrict__ lt,
                                            int* __restrict__ idxout,
                                            signed char* __restrict__ selmask,
                                            float* __restrict__ l3out) {
  int bh = blockIdx.x;
  int lane = threadIdx.x;
  __shared__ double vals[LQ];
  __shared__ float lsh[LQ];
  const double logL = 7.624618986159398;

  double v1 = -INFINITY, v2 = -INFINITY, v3 = -INFINITY;
  int i1 = LQ, i2 = LQ, i3 = LQ;

  for (int j = 0; j < 32; ++j) {
    int i = j * 64 + lane;
    const double* p0 = lt + ((size_t)bh * LQ + i) * 2;
    const double* p1 = lt + ((size_t)(64 + bh) * LQ + i) * 2;
    double l = p0[0] + p1[0];
    double tt = p0[1] + p1[1];
    double v = 0.125 * (tt / l) - log(l) + logL;
    vals[i] = v;
    lsh[i] = (float)l;               // softmax denominator for this row
    selmask[bh * LQ + i] = -1;
    if (v > v1)      { v3 = v2; i3 = i2; v2 = v1; i2 = i1; v1 = v; i1 = i; }
    else if (v > v2) { v3 = v2; i3 = i2; v2 = v;  i2 = i; }
    else if (v > v3) { v3 = v;  i3 = i; }
  }

  for (int u = 0; u < UU; ++u) {
    if (i1 == LQ) {
      v1 = v2 = v3 = -INFINITY;
      i1 = i2 = i3 = LQ;
      for (int j = 0; j < 32; ++j) {
        int i = j * 64 + lane;
        double v = vals[i];
        if (v > v1)      { v3 = v2; i3 = i2; v2 = v1; i2 = i1; v1 = v; i1 = i; }
        else if (v > v2) { v3 = v2; i3 = i2; v2 = v;  i2 = i; }
        else if (v > v3) { v3 = v;  i3 = i; }
      }
    }

    double gv = v1;
    int gi = i1;
#pragma unroll
    for (int m = 1; m < 64; m <<= 1) {
      double ov = __shfl_xor(gv, m);
      int oi = __shfl_xor(gi, m);
      if (ov > gv || (ov == gv && oi < gi)) { gv = ov; gi = oi; }
    }
    if (lane == 0) {
      idxout[bh * UU + u] = gi;
      selmask[bh * LQ + gi] = (signed char)u;
    }
    if ((gi & 63) == lane) {
      l3out[bh * UU + u] = lsh[gi];  // emit denominator of the winner
      vals[gi] = -INFINITY;
      v1 = v2; i1 = i2;
      v2 = v3; i2 = i3;
      v3 = -INFINITY; i3 = LQ;
    }
  }
}

// ---------------------------------------------------------------------------
// attn_w_pv r14: attn_w + attn_pv2 FUSED. l3 is known up front (topk2), so
// els gets NORMALIZED weights at first write -> wout is final immediately
// (the 40 MB read-normalize-rewrite round trip is gone) and PV runs in the
// same block straight off the resident els tile. opart partial written into
// this block's OWN already-consumed 32 KB ksp slice (disjoint per block;
// strictly after the last ksp read -> no race). l3i[38..47]=0 makes the pad
// rows clean zeros for the PV p-loop.
// ---------------------------------------------------------------------------
__global__ __launch_bounds__(256) void attn_w_pv(const float* __restrict__ Q,
                                                 const _Float16* __restrict__ ksp,
                                                 const int* __restrict__ sel,
                                                 const float* __restrict__ l3,
                                                 const float* __restrict__ V,
                                                 float* __restrict__ wout,
                                                 float* __restrict__ kspf) {
  int bh = blockIdx.x >> 4;
  int ks = blockIdx.x & 15;
  int b = bh >> 4, h = bh & 15;
  int t = threadIdx.x;
  int lane = t & 63, w = t >> 6;
  int quad = lane >> 4, l15 = lane & 15;

  __shared__ __align__(16) _Float16 kbuf[8192];   // 16 KB chunk image
  __shared__ float els[48 * 132];                 // 25.3 KB (normalized P)
  __shared__ int sidx[UU];
  __shared__ float l3i[48];                       // 1/l3 (0 for pad rows)

  if (t < UU) sidx[t] = sel[bh * UU + t];
  if (t < 48) l3i[t] = (t < UU) ? 1.f / l3[bh * UU + t] : 0.f;
  __syncthreads();

  f16x8 ahi[3][2], alo[3][2];
#pragma unroll
  for (int qt = 0; qt < 3; ++qt) {
    int u = qt * 16 + l15;
    if (u > 37) u = 37;                           // duplicate row 37 for pads
    const float* qrow = Q + ((size_t)(b * LQ + sidx[u])) * DM + h * DH;
#pragma unroll
    for (int c = 0; c < 2; ++c) {
      const float* p = qrow + c * 32 + quad * 8;
      float4 x0 = *(const float4*)p;
      float4 x1 = *(const float4*)(p + 4);
      f16x8 hi, lo;
#define QCV(i, xx) { float x_ = (xx); _Float16 hh = (_Float16)x_; hi[i] = hh; lo[i] = (_Float16)(x_ - (float)hh); }
      QCV(0, x0.x) QCV(1, x0.y) QCV(2, x0.z) QCV(3, x0.w)
      QCV(4, x1.x) QCV(5, x1.y) QCV(6, x1.z) QCV(7, x1.w)
#undef QCV
      ahi[qt][c] = hi;
      alo[qt][c] = lo;
    }
  }

  int bsw0 = quad ^ (l15 & 7);
  int bsw1 = (quad + 4) ^ (l15 & 7);
  const float C1 = 0.18033688011112042f;
  const char* gch = (const char*)(ksp + ((size_t)(bh * 32 + ks * 2)) * 8192);
  _Float16* khi = kbuf;
  _Float16* klo = kbuf + 4096;

  for (int chunk = 0; chunk < 2; ++chunk) {
    __syncthreads();
    {
      const char* gs = gch + (size_t)chunk * 16384 + (size_t)t * 16;
      char* ls = (char*)kbuf + (size_t)(w * 64) * 16;
#pragma unroll
      for (int i = 0; i < 4; ++i)
        GL2LDS16(gs + i * 4096, ls + i * 4096);
    }
    __syncthreads();
    int key = w * 16 + l15;
    f16x8 bhi0 = *(const f16x8*)(khi + key * 64 + bsw0 * 8);
    f16x8 bhi1 = *(const f16x8*)(khi + key * 64 + bsw1 * 8);
    f16x8 blo0 = *(const f16x8*)(klo + key * 64 + bsw0 * 8);
    f16x8 blo1 = *(const f16x8*)(klo + key * 64 + bsw1 * 8);
#pragma unroll
    for (int qt = 0; qt < 3; ++qt) {
      f32x4 cacc = {0.f, 0.f, 0.f, 0.f};
      cacc = __builtin_amdgcn_mfma_f32_16x16x32_f16(alo[qt][0], bhi0, cacc, 0, 0, 0);
      cacc = __builtin_amdgcn_mfma_f32_16x16x32_f16(alo[qt][1], bhi1, cacc, 0, 0, 0);
      cacc = __builtin_amdgcn_mfma_f32_16x16x32_f16(ahi[qt][0], blo0, cacc, 0, 0, 0);
      cacc = __builtin_amdgcn_mfma_f32_16x16x32_f16(ahi[qt][1], blo1, cacc, 0, 0, 0);
      cacc = __builtin_amdgcn_mfma_f32_16x16x32_f16(ahi[qt][0], bhi0, cacc, 0, 0, 0);
      cacc = __builtin_amdgcn_mfma_f32_16x16x32_f16(ahi[qt][1], bhi1, cacc, 0, 0, 0);
#pragma unroll
      for (int r = 0; r < 4; ++r) {
        int row = qt * 16 + quad * 4 + r;
        float e = EXP2F(cacc[r] * C1) * l3i[row];   // NORMALIZED weight
        els[row * 132 + chunk * 64 + w * 16 + l15] = e;
      }
    }
  }
  __syncthreads();

  // coalesced wout dump -- final normalized weights
  for (int i = t; i < UU * 128; i += 256) {
    int u = i >> 7, k = i & 127;
    wout[((size_t)(bh * UU + u)) * LQ + ks * 128 + k] = els[u * 132 + k];
  }

  // ---- PV phase (ex-attn_pv2), P read straight from els ----
  int d = t & 63, ug = t >> 6;
  const float* vbase = V + ((size_t)(b * LQ + ks * 128)) * DM + h * DH + d;
  float o[10];
#pragma unroll
  for (int p = 0; p < 10; ++p) o[p] = 0.f;

  for (int j4 = 0; j4 < 128; j4 += 4) {
    float v0 = vbase[(size_t)(j4 + 0) * DM];
    float v1 = vbase[(size_t)(j4 + 1) * DM];
    float v2 = vbase[(size_t)(j4 + 2) * DM];
    float v3 = vbase[(size_t)(j4 + 3) * DM];
#pragma unroll
    for (int p = 0; p < 10; ++p) {
      float4 pw = *(const float4*)(els + (ug + 4 * p) * 132 + j4);
      o[p] = fmaf(pw.x, v0, o[p]);
      o[p] = fmaf(pw.y, v1, o[p]);
      o[p] = fmaf(pw.z, v2, o[p]);
      o[p] = fmaf(pw.w, v3, o[p]);
    }
  }

  // opart partial -> first 9,728 B of this block's own ksp slice
  float* oslice = kspf + (size_t)(bh * 32 + ks * 2) * 4096;
#pragma unroll
  for (int p = 0; p < 10; ++p) {
    int u = ug + 4 * p;
    if (u < UU) oslice[u * 64 + d] = o[p];
  }
}

// ---------------------------------------------------------------------------
// writeout r14: dense-output pass; 16 pre-normalized partials live at the
// head of each (bh,ks) ksp slice (stride 2*4096 floats).
// ---------------------------------------------------------------------------
__global__ __launch_bounds__(256) void writeout_kernel(const signed char* __restrict__ selmask,
                                                       const float* __restrict__ kspf,
                                                       float* __restrict__ out) {
  int i2 = blockIdx.x * 256 + threadIdx.x;   // < 8,388,608 (exact grid)
  int d = i2 & 63;
  int h = (i2 >> 6) & 15;
  int q = (i2 >> 10) & 2047;
  int b = i2 >> 21;
  int bh = b * 16 + h;
  int u = selmask[bh * LQ + q];
  float val = 0.f;
  if (u >= 0) {
    const float* base = kspf + (size_t)(bh * 32) * 4096 + u * 64 + d;
    float s = 0.f;
#pragma unroll
    for (int p = 0; p < 16; ++p)
      s += base[(size_t)(p * 2) * 4096];
    val = s;
  }
  out[i2] = val;
}

extern "C" void kernel_launch(void* const* d_in, const int* in_sizes, int n_in,
                              void* d_out, int out_size, void* d_ws, size_t ws_size,
                              hipStream_t stream) {
  (void)in_sizes; (void)n_in;
  if (ws_size < F_NEED) return;   // fail visibly (poisoned out) over UB; r8 confirmed fit
  const float* Q = (const float*)d_in[0];
  const float* K = (const float*)d_in[1];
  const float* V = (const float*)d_in[2];
  float* out = (float*)d_out;
  float* wout = out + (size_t)4 * LQ * DM;
  char* ws = (char*)d_ws;

  double* lt = (double*)ws;
  int* sel = (int*)(ws + F_OFF_SEL);
  float* l3 = (float*)(ws + F_OFF_L3);
  signed char* mask = (signed char*)(ws + F_OFF_MASK);
  _Float16* ksp = (_Float16*)(ws + F_OFF_KSP);
  float* kspf = (float*)(ws + F_OFF_KSP);   // opart partials (per-block self-alias)

  ksplit_kernel<<<4096, 256, 0, stream>>>(K, ksp);
  kl_mfma2<<<2048, 256, 0, stream>>>(Q, ksp, lt);
  topk2<<<NBH, 64, 0, stream>>>(lt, sel, mask, l3);
  attn_w_pv<<<NBH * 16, 256, 0, stream>>>(Q, ksp, sel, l3, V, wout, kspf);
  writeout_kernel<<<(4 * LQ * DM) / 256, 256, 0, stream>>>(mask, kspf, out);
}

// Round 7
// 341.192 us; speedup vs baseline: 1.0110x; 1.0110x over previous
//
#include <hip/hip_runtime.h>
#include <math.h>

#define LQ 2048
#define DM 1024
#define NH 16
#define DH 64
#define UU 38
#define NBH 64            // B*NH = 4*16
#define SCALE 0.125f      // 1/sqrt(64)

typedef _Float16 f16x8 __attribute__((ext_vector_type(8)));
typedef float f32x4 __attribute__((ext_vector_type(4)));
typedef float f32x2 __attribute__((ext_vector_type(2)));

#if __has_builtin(__builtin_amdgcn_exp2f)
#define EXP2F(x) __builtin_amdgcn_exp2f(x)
#else
#define EXP2F(x) exp2f(x)
#endif

// async global->LDS DMA, 16B per lane. LDS dest is wave-uniform base + lane*16.
#define GL2LDS16(gp, lp)                                           \
  __builtin_amdgcn_global_load_lds(                                \
      (const __attribute__((address_space(1))) void*)(gp),         \
      (__attribute__((address_space(3))) void*)(lp), 16, 0, 0)

// ---- workspace layout (bytes), total 40,700,928 ----
//   lt    : [2][64][2048][2] f64           [0, 4194304)
//   sel   : 64*38 int                       +9728
//   l3    : 64*38 f32 (f64-accurate softmax denominators, from topk2)
//   mask  : (DEAD in r16 -- writeout deleted; slot kept for layout stability)
//   ksp   : [64][32][8192] f16 @ 7146496    (33,554,432 B)
#define F_OFF_SEL   4194304
#define F_OFF_L3    4204032
#define F_OFF_MASK  4213760
#define F_OFF_LPART 4344832
#define F_OFF_KSP   7146496
#define F_NEED      40700928ull

// ---------------------------------------------------------------------------
// ksplit r16: K fp32 -> fp16 hi/lo split (unchanged, validated) PLUS the
// dense-output zero fill (out is atomicAdd-accumulated by attn_w_pv later in
// the same launch chain, so every element must be written each launch --
// re-poison safe). 1M threads x 32B covers the 33.5MB out exactly.
// ---------------------------------------------------------------------------
__global__ __launch_bounds__(256) void ksplit_kernel(const float* __restrict__ K,
                                                     _Float16* __restrict__ ksp,
                                                     float* __restrict__ outz) {
  int idx = blockIdx.x * 256 + threadIdx.x;   // 1,048,576 total
  int p = idx & 7;
  int k = (idx >> 3) & 63;
  int kc = (idx >> 9) & 31;
  int bh = idx >> 14;
  int b = bh >> 4, h = bh & 15;
  const float* src = K + ((size_t)(b * LQ + kc * 64 + k)) * DM + h * DH + (p ^ (k & 7)) * 8;
  float4 x0 = *(const float4*)src;
  float4 x1 = *(const float4*)(src + 4);
  f16x8 hi, lo;
#define KCV(i, xx) { float x_ = (xx); _Float16 hh = (_Float16)x_; hi[i] = hh; lo[i] = (_Float16)(x_ - (float)hh); }
  KCV(0, x0.x) KCV(1, x0.y) KCV(2, x0.z) KCV(3, x0.w)
  KCV(4, x1.x) KCV(5, x1.y) KCV(6, x1.z) KCV(7, x1.w)
#undef KCV
  _Float16* base = ksp + ((size_t)(bh * 32 + kc)) * 8192;
  *(f16x8*)(base + k * 64 + p * 8) = hi;
  *(f16x8*)(base + 4096 + k * 64 + p * 8) = lo;

  float4 z = {0.f, 0.f, 0.f, 0.f};
  *(float4*)(outz + (size_t)idx * 8) = z;
  *(float4*)(outz + (size_t)idx * 8 + 4) = z;
}

// ---------------------------------------------------------------------------
// kl_mfma2 r16: r12 structure EXACTLY (validated 127.5us) + ONE isolated
// change: s_setprio(1) tight around each 6-MFMA dependent cluster (T5).
// ~6 independent 4-wave blocks/CU drift in phase -> MFMA-phase waves win
// issue arbitration over exp-phase waves. Directly readable in top-5.
// ---------------------------------------------------------------------------
__global__ __launch_bounds__(256) void kl_mfma2(const float* __restrict__ Q,
                                                const _Float16* __restrict__ ksp,
                                                double* __restrict__ lt) {
  int bh = blockIdx.x & 63;
  int qc = (blockIdx.x >> 6) & 15;
  int sp = blockIdx.x >> 10;
  int b = bh >> 4, h = bh & 15;
  int t = threadIdx.x;
  int lane = t & 63, w = t >> 6;
  int quad = lane >> 4, l15 = lane & 15;

  __shared__ __align__(16) _Float16 kbuf[8192];   // 16 KB = 2 x 8 KB dbuf

  f16x8 ahi[2][2], alo[2][2];
  {
    const float* qrow = Q + ((size_t)(b * LQ + qc * 128)) * DM + h * DH;
#pragma unroll
    for (int qt = 0; qt < 2; ++qt)
#pragma unroll
      for (int c = 0; c < 2; ++c) {
        const float* p = qrow + (size_t)(w * 32 + qt * 16 + l15) * DM + c * 32 + quad * 8;
        float4 x0 = *(const float4*)p;
        float4 x1 = *(const float4*)(p + 4);
        f16x8 hi, lo;
#define QCV(i, xx) { float x_ = (xx); _Float16 hh = (_Float16)x_; hi[i] = hh; lo[i] = (_Float16)(x_ - (float)hh); }
        QCV(0, x0.x) QCV(1, x0.y) QCV(2, x0.z) QCV(3, x0.w)
        QCV(4, x1.x) QCV(5, x1.y) QCV(6, x1.z) QCV(7, x1.w)
#undef QCV
        ahi[qt][c] = hi;
        alo[qt][c] = lo;
      }
  }

  int bsw0 = quad ^ (l15 & 7);
  int bsw1 = (quad + 4) ^ (l15 & 7);
  const float C1 = 0.18033688011112042f;  // SCALE * log2(e)

  double l64[2][4], t64[2][4];
#pragma unroll
  for (int qt = 0; qt < 2; ++qt)
#pragma unroll
    for (int r = 0; r < 4; ++r) { l64[qt][r] = 0.0; t64[qt][r] = 0.0; }

  const _Float16* khiA = kbuf;
  const _Float16* kloA = kbuf + 2048;
  const _Float16* khiB = kbuf + 4096;
  const _Float16* kloB = kbuf + 6144;

  const char* gp = (const char*)(ksp + ((size_t)(bh * 32 + sp * 16)) * 8192) + t * 16;
  char* ldsA = (char*)kbuf + w * 1024;          // wave-uniform dests
  char* ldsB = (char*)kbuf + 8192 + w * 1024;

#define KLSTEP(KHI, KLO)                                                        \
  _Pragma("unroll")                                                             \
  for (int kt = 0; kt < 2; ++kt) {                                              \
    int key = kt * 16 + l15;                                                    \
    f16x8 bhi0 = *(const f16x8*)((KHI) + key * 64 + bsw0 * 8);                  \
    f16x8 bhi1 = *(const f16x8*)((KHI) + key * 64 + bsw1 * 8);                  \
    f16x8 blo0 = *(const f16x8*)((KLO) + key * 64 + bsw0 * 8);                  \
    f16x8 blo1 = *(const f16x8*)((KLO) + key * 64 + bsw1 * 8);                  \
    _Pragma("unroll")                                                           \
    for (int qt = 0; qt < 2; ++qt) {                                            \
      f32x4 cacc = {0.f, 0.f, 0.f, 0.f};                                        \
      __builtin_amdgcn_s_setprio(1);                                            \
      cacc = __builtin_amdgcn_mfma_f32_16x16x32_f16(alo[qt][0], bhi0, cacc, 0, 0, 0); \
      cacc = __builtin_amdgcn_mfma_f32_16x16x32_f16(alo[qt][1], bhi1, cacc, 0, 0, 0); \
      cacc = __builtin_amdgcn_mfma_f32_16x16x32_f16(ahi[qt][0], blo0, cacc, 0, 0, 0); \
      cacc = __builtin_amdgcn_mfma_f32_16x16x32_f16(ahi[qt][1], blo1, cacc, 0, 0, 0); \
      cacc = __builtin_amdgcn_mfma_f32_16x16x32_f16(ahi[qt][0], bhi0, cacc, 0, 0, 0); \
      cacc = __builtin_amdgcn_mfma_f32_16x16x32_f16(ahi[qt][1], bhi1, cacc, 0, 0, 0); \
      __builtin_amdgcn_s_setprio(0);                                            \
      _Pragma("unroll")                                                         \
      for (int rp = 0; rp < 2; ++rp) {                                          \
        f32x2 rr = { cacc[2 * rp], cacc[2 * rp + 1] };                          \
        f32x2 sc = rr * C1;                    /* v_pk_mul_f32 */               \
        f32x2 e  = { EXP2F(sc[0]), EXP2F(sc[1]) };                              \
        l32[qt][rp] += e;                      /* v_pk_add_f32 */               \
        t32[qt][rp] += rr * e;                 /* v_pk_fma_f32 */               \
      }                                                                         \
    }                                                                           \
  }

  GL2LDS16(gp, ldsA);
  GL2LDS16(gp + 8192, ldsA + 4096);
  __syncthreads();

  for (int j = 0; j < 16; ++j) {
    GL2LDS16(gp + 4096, ldsB);
    GL2LDS16(gp + 12288, ldsB + 4096);

    f32x2 l32[2][2], t32[2][2];
#pragma unroll
    for (int qt = 0; qt < 2; ++qt)
#pragma unroll
      for (int rp = 0; rp < 2; ++rp) {
        l32[qt][rp] = (f32x2){0.f, 0.f};
        t32[qt][rp] = (f32x2){0.f, 0.f};
      }

    KLSTEP(khiA, kloA)
    __syncthreads();

    if (j < 15) {
      gp += 16384;
      GL2LDS16(gp, ldsA);
      GL2LDS16(gp + 8192, ldsA + 4096);
    }

    KLSTEP(khiB, kloB)

#pragma unroll
    for (int qt = 0; qt < 2; ++qt)
#pragma unroll
      for (int rp = 0; rp < 2; ++rp)
#pragma unroll
        for (int c = 0; c < 2; ++c) {
          l64[qt][rp * 2 + c] += (double)l32[qt][rp][c];
          t64[qt][rp * 2 + c] += (double)t32[qt][rp][c];
        }
    __syncthreads();
  }
#undef KLSTEP

#pragma unroll
  for (int qt = 0; qt < 2; ++qt)
#pragma unroll
    for (int r = 0; r < 4; ++r) {
      double lv = l64[qt][r], tv = t64[qt][r];
#pragma unroll
      for (int m = 1; m < 16; m <<= 1) {
        lv += __shfl_xor(lv, m);
        tv += __shfl_xor(tv, m);
      }
      if (l15 == 0) {
        int qg = qc * 128 + w * 32 + qt * 16 + quad * 4 + r;
        double* dst = lt + ((size_t)(sp * 64 + bh) * LQ + qg) * 2;
        dst[0] = lv;
        dst[1] = tv;
      }
    }
}

// ---------------------------------------------------------------------------
// topk2 r16: r13/r14 register top-3 scheme (validated); selmask DELETED
// (writeout is gone -- nothing consumes it). Emits sel + f64-accurate l3.
// ---------------------------------------------------------------------------
__global__ __launch_bounds__(64) void topk2(const double* __restrict__ lt,
                                            int* __restrict__ idxout,
                                            float* __restrict__ l3out) {
  int bh = blockIdx.x;
  int lane = threadIdx.x;
  __shared__ double vals[LQ];
  __shared__ float lsh[LQ];
  const double logL = 7.624618986159398;

  double v1 = -INFINITY, v2 = -INFINITY, v3 = -INFINITY;
  int i1 = LQ, i2 = LQ, i3 = LQ;

  for (int j = 0; j < 32; ++j) {
    int i = j * 64 + lane;
    const double* p0 = lt + ((size_t)bh * LQ + i) * 2;
    const double* p1 = lt + ((size_t)(64 + bh) * LQ + i) * 2;
    double l = p0[0] + p1[0];
    double tt = p0[1] + p1[1];
    double v = 0.125 * (tt / l) - log(l) + logL;
    vals[i] = v;
    lsh[i] = (float)l;               // softmax denominator for this row
    if (v > v1)      { v3 = v2; i3 = i2; v2 = v1; i2 = i1; v1 = v; i1 = i; }
    else if (v > v2) { v3 = v2; i3 = i2; v2 = v;  i2 = i; }
    else if (v > v3) { v3 = v;  i3 = i; }
  }

  for (int u = 0; u < UU; ++u) {
    if (i1 == LQ) {
      v1 = v2 = v3 = -INFINITY;
      i1 = i2 = i3 = LQ;
      for (int j = 0; j < 32; ++j) {
        int i = j * 64 + lane;
        double v = vals[i];
        if (v > v1)      { v3 = v2; i3 = i2; v2 = v1; i2 = i1; v1 = v; i1 = i; }
        else if (v > v2) { v3 = v2; i3 = i2; v2 = v;  i2 = i; }
        else if (v > v3) { v3 = v;  i3 = i; }
      }
    }

    double gv = v1;
    int gi = i1;
#pragma unroll
    for (int m = 1; m < 64; m <<= 1) {
      double ov = __shfl_xor(gv, m);
      int oi = __shfl_xor(gi, m);
      if (ov > gv || (ov == gv && oi < gi)) { gv = ov; gi = oi; }
    }
    if (lane == 0) idxout[bh * UU + u] = gi;
    if ((gi & 63) == lane) {
      l3out[bh * UU + u] = lsh[gi];  // emit denominator of the winner
      vals[gi] = -INFINITY;
      v1 = v2; i1 = i2;
      v2 = v3; i2 = i3;
      v3 = -INFINITY; i3 = LQ;
    }
  }
}

// ---------------------------------------------------------------------------
// attn_w_pv r16: els holds UNNORMALIZED e (r13 rounding profile); wout dump
// scales by 1/l3 at write; PV accumulates unnormalized then one end-scale
// and atomicAdds the final value straight into out (zeroed by ksplit).
// 16-way contention per address, device-scope f32 atomics. writeout deleted.
// ---------------------------------------------------------------------------
__global__ __launch_bounds__(256) void attn_w_pv(const float* __restrict__ Q,
                                                 const _Float16* __restrict__ ksp,
                                                 const int* __restrict__ sel,
                                                 const float* __restrict__ l3,
                                                 const float* __restrict__ V,
                                                 float* __restrict__ wout,
                                                 float* __restrict__ out) {
  int bh = blockIdx.x >> 4;
  int ks = blockIdx.x & 15;
  int b = bh >> 4, h = bh & 15;
  int t = threadIdx.x;
  int lane = t & 63, w = t >> 6;
  int quad = lane >> 4, l15 = lane & 15;

  __shared__ __align__(16) _Float16 kbuf[8192];   // 16 KB chunk image
  __shared__ float els[48 * 132];                 // 25.3 KB (UNNORMALIZED e)
  __shared__ int sidx[UU];
  __shared__ float l3i[48];                       // 1/l3 (0 for pad rows)

  if (t < UU) sidx[t] = sel[bh * UU + t];
  if (t < 48) l3i[t] = (t < UU) ? 1.f / l3[bh * UU + t] : 0.f;
  __syncthreads();

  f16x8 ahi[3][2], alo[3][2];
#pragma unroll
  for (int qt = 0; qt < 3; ++qt) {
    int u = qt * 16 + l15;
    if (u > 37) u = 37;                           // duplicate row 37 for pads
    const float* qrow = Q + ((size_t)(b * LQ + sidx[u])) * DM + h * DH;
#pragma unroll
    for (int c = 0; c < 2; ++c) {
      const float* p = qrow + c * 32 + quad * 8;
      float4 x0 = *(const float4*)p;
      float4 x1 = *(const float4*)(p + 4);
      f16x8 hi, lo;
#define QCV(i, xx) { float x_ = (xx); _Float16 hh = (_Float16)x_; hi[i] = hh; lo[i] = (_Float16)(x_ - (float)hh); }
      QCV(0, x0.x) QCV(1, x0.y) QCV(2, x0.z) QCV(3, x0.w)
      QCV(4, x1.x) QCV(5, x1.y) QCV(6, x1.z) QCV(7, x1.w)
#undef QCV
      ahi[qt][c] = hi;
      alo[qt][c] = lo;
    }
  }

  int bsw0 = quad ^ (l15 & 7);
  int bsw1 = (quad + 4) ^ (l15 & 7);
  const float C1 = 0.18033688011112042f;
  const char* gch = (const char*)(ksp + ((size_t)(bh * 32 + ks * 2)) * 8192);
  _Float16* khi = kbuf;
  _Float16* klo = kbuf + 4096;

  for (int chunk = 0; chunk < 2; ++chunk) {
    __syncthreads();
    {
      const char* gs = gch + (size_t)chunk * 16384 + (size_t)t * 16;
      char* ls = (char*)kbuf + (size_t)(w * 64) * 16;
#pragma unroll
      for (int i = 0; i < 4; ++i)
        GL2LDS16(gs + i * 4096, ls + i * 4096);
    }
    __syncthreads();
    int key = w * 16 + l15;
    f16x8 bhi0 = *(const f16x8*)(khi + key * 64 + bsw0 * 8);
    f16x8 bhi1 = *(const f16x8*)(khi + key * 64 + bsw1 * 8);
    f16x8 blo0 = *(const f16x8*)(klo + key * 64 + bsw0 * 8);
    f16x8 blo1 = *(const f16x8*)(klo + key * 64 + bsw1 * 8);
#pragma unroll
    for (int qt = 0; qt < 3; ++qt) {
      f32x4 cacc = {0.f, 0.f, 0.f, 0.f};
      cacc = __builtin_amdgcn_mfma_f32_16x16x32_f16(alo[qt][0], bhi0, cacc, 0, 0, 0);
      cacc = __builtin_amdgcn_mfma_f32_16x16x32_f16(alo[qt][1], bhi1, cacc, 0, 0, 0);
      cacc = __builtin_amdgcn_mfma_f32_16x16x32_f16(ahi[qt][0], blo0, cacc, 0, 0, 0);
      cacc = __builtin_amdgcn_mfma_f32_16x16x32_f16(ahi[qt][1], blo1, cacc, 0, 0, 0);
      cacc = __builtin_amdgcn_mfma_f32_16x16x32_f16(ahi[qt][0], bhi0, cacc, 0, 0, 0);
      cacc = __builtin_amdgcn_mfma_f32_16x16x32_f16(ahi[qt][1], bhi1, cacc, 0, 0, 0);
#pragma unroll
      for (int r = 0; r < 4; ++r) {
        int row = qt * 16 + quad * 4 + r;
        els[row * 132 + chunk * 64 + w * 16 + l15] = EXP2F(cacc[r] * C1);
      }
    }
  }
  __syncthreads();

  // coalesced wout dump -- normalized at write (single extra rounding here
  // only; PV path keeps the r13 single-end-rounding profile)
  for (int i = t; i < UU * 128; i += 256) {
    int u = i >> 7, k = i & 127;
    wout[((size_t)(bh * UU + u)) * LQ + ks * 128 + k] = els[u * 132 + k] * l3i[u];
  }

  // ---- PV phase: unnormalized accumulate, one end-scale, atomic scatter ----
  int d = t & 63, ug = t >> 6;
  const float* vbase = V + ((size_t)(b * LQ + ks * 128)) * DM + h * DH + d;
  float o[10];
#pragma unroll
  for (int p = 0; p < 10; ++p) o[p] = 0.f;

  for (int j4 = 0; j4 < 128; j4 += 4) {
    float v0 = vbase[(size_t)(j4 + 0) * DM];
    float v1 = vbase[(size_t)(j4 + 1) * DM];
    float v2 = vbase[(size_t)(j4 + 2) * DM];
    float v3 = vbase[(size_t)(j4 + 3) * DM];
#pragma unroll
    for (int p = 0; p < 10; ++p) {
      float4 pw = *(const float4*)(els + (ug + 4 * p) * 132 + j4);
      o[p] = fmaf(pw.x, v0, o[p]);
      o[p] = fmaf(pw.y, v1, o[p]);
      o[p] = fmaf(pw.z, v2, o[p]);
      o[p] = fmaf(pw.w, v3, o[p]);
    }
  }

#pragma unroll
  for (int p = 0; p < 10; ++p) {
    int u = ug + 4 * p;
    if (u < UU) {
      float* dst = out + ((size_t)(b * LQ + sidx[u])) * DM + h * DH + d;
      atomicAdd(dst, o[p] * l3i[u]);
    }
  }
}

extern "C" void kernel_launch(void* const* d_in, const int* in_sizes, int n_in,
                              void* d_out, int out_size, void* d_ws, size_t ws_size,
                              hipStream_t stream) {
  (void)in_sizes; (void)n_in;
  if (ws_size < F_NEED) return;   // fail visibly (poisoned out) over UB
  const float* Q = (const float*)d_in[0];
  const float* K = (const float*)d_in[1];
  const float* V = (const float*)d_in[2];
  float* out = (float*)d_out;
  float* wout = out + (size_t)4 * LQ * DM;
  char* ws = (char*)d_ws;

  double* lt = (double*)ws;
  int* sel = (int*)(ws + F_OFF_SEL);
  float* l3 = (float*)(ws + F_OFF_L3);
  _Float16* ksp = (_Float16*)(ws + F_OFF_KSP);

  ksplit_kernel<<<4096, 256, 0, stream>>>(K, ksp, out);
  kl_mfma2<<<2048, 256, 0, stream>>>(Q, ksp, lt);
  topk2<<<NBH, 64, 0, stream>>>(lt, sel, l3);
  attn_w_pv<<<NBH * 16, 256, 0, stream>>>(Q, ksp, sel, l3, V, wout, out);
}

// Round 8
// 340.926 us; speedup vs baseline: 1.0118x; 1.0008x over previous
//
#include <hip/hip_runtime.h>
#include <math.h>

#define LQ 2048
#define DM 1024
#define NH 16
#define DH 64
#define UU 38
#define NBH 64            // B*NH = 4*16
#define SCALE 0.125f      // 1/sqrt(64)

typedef _Float16 f16x8 __attribute__((ext_vector_type(8)));
typedef float f32x4 __attribute__((ext_vector_type(4)));
typedef float f32x2 __attribute__((ext_vector_type(2)));

#if __has_builtin(__builtin_amdgcn_exp2f)
#define EXP2F(x) __builtin_amdgcn_exp2f(x)
#else
#define EXP2F(x) exp2f(x)
#endif

// async global->LDS DMA, 16B per lane. LDS dest is wave-uniform base + lane*16.
#define GL2LDS16(gp, lp)                                           \
  __builtin_amdgcn_global_load_lds(                                \
      (const __attribute__((address_space(1))) void*)(gp),         \
      (__attribute__((address_space(3))) void*)(lp), 16, 0, 0)

// ---- workspace layout (bytes), total 40,700,928 ----
//   lt    : [2][64][2048][2] f64           [0, 4194304)
//   sel   : 64*38 int                       +9728
//   l3    : 64*38 f32 (f64-accurate softmax denominators, from topk2)
//   ksp   : [64][32][8192] f16 @ 7146496    (33,554,432 B)
#define F_OFF_SEL   4194304
#define F_OFF_L3    4204032
#define F_OFF_MASK  4213760
#define F_OFF_LPART 4344832
#define F_OFF_KSP   7146496
#define F_NEED      40700928ull

// ---------------------------------------------------------------------------
// ksplit: K fp32 -> fp16 hi/lo split + dense-output zero fill. Unchanged
// (validated r16).
// ---------------------------------------------------------------------------
__global__ __launch_bounds__(256) void ksplit_kernel(const float* __restrict__ K,
                                                     _Float16* __restrict__ ksp,
                                                     float* __restrict__ outz) {
  int idx = blockIdx.x * 256 + threadIdx.x;   // 1,048,576 total
  int p = idx & 7;
  int k = (idx >> 3) & 63;
  int kc = (idx >> 9) & 31;
  int bh = idx >> 14;
  int b = bh >> 4, h = bh & 15;
  const float* src = K + ((size_t)(b * LQ + kc * 64 + k)) * DM + h * DH + (p ^ (k & 7)) * 8;
  float4 x0 = *(const float4*)src;
  float4 x1 = *(const float4*)(src + 4);
  f16x8 hi, lo;
#define KCV(i, xx) { float x_ = (xx); _Float16 hh = (_Float16)x_; hi[i] = hh; lo[i] = (_Float16)(x_ - (float)hh); }
  KCV(0, x0.x) KCV(1, x0.y) KCV(2, x0.z) KCV(3, x0.w)
  KCV(4, x1.x) KCV(5, x1.y) KCV(6, x1.z) KCV(7, x1.w)
#undef KCV
  _Float16* base = ksp + ((size_t)(bh * 32 + kc)) * 8192;
  *(f16x8*)(base + k * 64 + p * 8) = hi;
  *(f16x8*)(base + 4096 + k * 64 + p * 8) = lo;

  float4 z = {0.f, 0.f, 0.f, 0.f};
  *(float4*)(outz + (size_t)idx * 8) = z;
  *(float4*)(outz + (size_t)idx * 8 + 4) = z;
}

// ---------------------------------------------------------------------------
// kl_mfma2 r17: counted-vmcnt pipeline (T3+T4). Six probes showed the wall
// (127us) is stall-bound, not pipe-bound: MFMA busy 50us/CU, wall 127 -> 39%
// util of the binding pipe. The stall is __syncthreads' forced
// "s_waitcnt vmcnt(0)" before every s_barrier (drains the NEXT tile's
// prefetch too). Fix per m218: 3-buffer ring, raw s_barrier, per-iter
// "s_waitcnt vmcnt(2)" -- wait own stage(i), keep stage(i+1) in flight
// across the barrier; never drain to 0 in the loop. Wait-BEFORE-barrier
// makes the per-wave wait global-safe. One barrier per 32-key sub-iter
// separates stage(i+2) writes from compute(i-1) reads of the same buffer.
// x6 unroll keeps buffer indices + fold parities static. Math/order/fold
// cadence bit-identical to r12 (validated).
// ---------------------------------------------------------------------------
__global__ __launch_bounds__(256) void kl_mfma2(const float* __restrict__ Q,
                                                const _Float16* __restrict__ ksp,
                                                double* __restrict__ lt) {
  int bh = blockIdx.x & 63;
  int qc = (blockIdx.x >> 6) & 15;
  int sp = blockIdx.x >> 10;
  int b = bh >> 4, h = bh & 15;
  int t = threadIdx.x;
  int lane = t & 63, w = t >> 6;
  int quad = lane >> 4, l15 = lane & 15;

  __shared__ __align__(16) _Float16 kbuf[12288];   // 24 KB = 3 x 8 KB ring

  f16x8 ahi[2][2], alo[2][2];
  {
    const float* qrow = Q + ((size_t)(b * LQ + qc * 128)) * DM + h * DH;
#pragma unroll
    for (int qt = 0; qt < 2; ++qt)
#pragma unroll
      for (int c = 0; c < 2; ++c) {
        const float* p = qrow + (size_t)(w * 32 + qt * 16 + l15) * DM + c * 32 + quad * 8;
        float4 x0 = *(const float4*)p;
        float4 x1 = *(const float4*)(p + 4);
        f16x8 hi, lo;
#define QCV(i, xx) { float x_ = (xx); _Float16 hh = (_Float16)x_; hi[i] = hh; lo[i] = (_Float16)(x_ - (float)hh); }
        QCV(0, x0.x) QCV(1, x0.y) QCV(2, x0.z) QCV(3, x0.w)
        QCV(4, x1.x) QCV(5, x1.y) QCV(6, x1.z) QCV(7, x1.w)
#undef QCV
        ahi[qt][c] = hi;
        alo[qt][c] = lo;
      }
  }

  int bsw0 = quad ^ (l15 & 7);
  int bsw1 = (quad + 4) ^ (l15 & 7);
  const float C1 = 0.18033688011112042f;  // SCALE * log2(e)

  double l64[2][4], t64[2][4];
#pragma unroll
  for (int qt = 0; qt < 2; ++qt)
#pragma unroll
    for (int r = 0; r < 4; ++r) { l64[qt][r] = 0.0; t64[qt][r] = 0.0; }

  f32x2 l32[2][2], t32[2][2];
#pragma unroll
  for (int qt = 0; qt < 2; ++qt)
#pragma unroll
    for (int rp = 0; rp < 2; ++rp) {
      l32[qt][rp] = (f32x2){0.f, 0.f};
      t32[qt][rp] = (f32x2){0.f, 0.f};
    }

  // per-lane global src base; sub-chunk m: hi at +(m>>1)*16384+(m&1)*4096,
  // lo at hi+8192 (pair layout: [hiE][hiO][loE][loO] per 16 KB pair).
  const char* gch8 = (const char*)(ksp + ((size_t)(bh * 32 + sp * 16)) * 8192) + t * 16;
  // wave-uniform LDS dest base; buffer n: hi at +n*8192, lo at +n*8192+4096.
  char* lbb = (char*)kbuf + w * 1024;

#define STAGE(m_, n_)                                                           \
  { const char* s_ = gch8 + (((m_) >> 1) * 16384) + (((m_) & 1) * 4096);        \
    GL2LDS16(s_, lbb + (n_) * 8192);                                            \
    GL2LDS16(s_ + 8192, lbb + (n_) * 8192 + 4096); }

  // 32-key compute of buffer n (hi = kbuf+n*4096, lo = +2048 f16 units)
#define KLSTEP(N_)                                                              \
  _Pragma("unroll")                                                             \
  for (int kt = 0; kt < 2; ++kt) {                                              \
    int key = kt * 16 + l15;                                                    \
    const _Float16* KHI = kbuf + (N_) * 4096;                                   \
    const _Float16* KLO = KHI + 2048;                                           \
    f16x8 bhi0 = *(const f16x8*)(KHI + key * 64 + bsw0 * 8);                    \
    f16x8 bhi1 = *(const f16x8*)(KHI + key * 64 + bsw1 * 8);                    \
    f16x8 blo0 = *(const f16x8*)(KLO + key * 64 + bsw0 * 8);                    \
    f16x8 blo1 = *(const f16x8*)(KLO + key * 64 + bsw1 * 8);                    \
    _Pragma("unroll")                                                           \
    for (int qt = 0; qt < 2; ++qt) {                                            \
      f32x4 cacc = {0.f, 0.f, 0.f, 0.f};                                        \
      __builtin_amdgcn_s_setprio(1);                                            \
      cacc = __builtin_amdgcn_mfma_f32_16x16x32_f16(alo[qt][0], bhi0, cacc, 0, 0, 0); \
      cacc = __builtin_amdgcn_mfma_f32_16x16x32_f16(alo[qt][1], bhi1, cacc, 0, 0, 0); \
      cacc = __builtin_amdgcn_mfma_f32_16x16x32_f16(ahi[qt][0], blo0, cacc, 0, 0, 0); \
      cacc = __builtin_amdgcn_mfma_f32_16x16x32_f16(ahi[qt][1], blo1, cacc, 0, 0, 0); \
      cacc = __builtin_amdgcn_mfma_f32_16x16x32_f16(ahi[qt][0], bhi0, cacc, 0, 0, 0); \
      cacc = __builtin_amdgcn_mfma_f32_16x16x32_f16(ahi[qt][1], bhi1, cacc, 0, 0, 0); \
      __builtin_amdgcn_s_setprio(0);                                            \
      _Pragma("unroll")                                                         \
      for (int rp = 0; rp < 2; ++rp) {                                          \
        f32x2 rr = { cacc[2 * rp], cacc[2 * rp + 1] };                          \
        f32x2 sc = rr * C1;                                                     \
        f32x2 e  = { EXP2F(sc[0]), EXP2F(sc[1]) };                              \
        l32[qt][rp] += e;                                                       \
        t32[qt][rp] += rr * e;                                                  \
      }                                                                         \
    }                                                                           \
  }

#define FOLD()                                                                  \
  { _Pragma("unroll")                                                           \
    for (int qt = 0; qt < 2; ++qt)                                              \
      _Pragma("unroll")                                                         \
      for (int rp = 0; rp < 2; ++rp)                                            \
        _Pragma("unroll")                                                       \
        for (int c = 0; c < 2; ++c) {                                           \
          l64[qt][rp * 2 + c] += (double)l32[qt][rp][c];                        \
          t64[qt][rp * 2 + c] += (double)t32[qt][rp][c];                        \
          l32[qt][rp][c] = 0.f;                                                 \
          t32[qt][rp][c] = 0.f;                                                 \
        } }

  // SUB(i, n, vm): wait own stage(i) [vmcnt(vm) -- stage(i+1) stays in
  // flight], barrier, issue stage(i+2), compute buffer n. sched_barrier
  // pins the wait (rule #18).
#define SUB2(i_, n_, vm_)                                                       \
  asm volatile("s_waitcnt vmcnt(" vm_ ")" ::: "memory");                        \
  __builtin_amdgcn_sched_barrier(0);                                            \
  __builtin_amdgcn_s_barrier();

  // prologue: stage sub-chunks 0,1 into buffers 0,1
  STAGE(0, 0)
  STAGE(1, 1)

  for (int k5 = 0; k5 < 5; ++k5) {
    int i0 = 6 * k5;
    SUB2(i0 + 0, 0, "2") STAGE(i0 + 2, 2) KLSTEP(0)
    SUB2(i0 + 1, 1, "2") STAGE(i0 + 3, 0) KLSTEP(1) FOLD()
    SUB2(i0 + 2, 2, "2") STAGE(i0 + 4, 1) KLSTEP(2)
    SUB2(i0 + 3, 0, "2") STAGE(i0 + 5, 2) KLSTEP(0) FOLD()
    SUB2(i0 + 4, 1, "2") STAGE(i0 + 6, 0) KLSTEP(1)
    SUB2(i0 + 5, 2, "2") STAGE(i0 + 7, 1) KLSTEP(2) FOLD()
  }
  // peeled: i=30 (buffer 0, stage(31) still in flight), i=31 (buffer 1)
  SUB2(30, 0, "2") KLSTEP(0)
  SUB2(31, 1, "0") KLSTEP(1) FOLD()

#undef SUB2
#undef STAGE
#undef KLSTEP
#undef FOLD

#pragma unroll
  for (int qt = 0; qt < 2; ++qt)
#pragma unroll
    for (int r = 0; r < 4; ++r) {
      double lv = l64[qt][r], tv = t64[qt][r];
#pragma unroll
      for (int m = 1; m < 16; m <<= 1) {
        lv += __shfl_xor(lv, m);
        tv += __shfl_xor(tv, m);
      }
      if (l15 == 0) {
        int qg = qc * 128 + w * 32 + qt * 16 + quad * 4 + r;
        double* dst = lt + ((size_t)(sp * 64 + bh) * LQ + qg) * 2;
        dst[0] = lv;
        dst[1] = tv;
      }
    }
}

// ---------------------------------------------------------------------------
// topk2: r16 state (validated) -- register top-3, emits sel + f64-accurate l3.
// ---------------------------------------------------------------------------
__global__ __launch_bounds__(64) void topk2(const double* __restrict__ lt,
                                            int* __restrict__ idxout,
                                            float* __restrict__ l3out) {
  int bh = blockIdx.x;
  int lane = threadIdx.x;
  __shared__ double vals[LQ];
  __shared__ float lsh[LQ];
  const double logL = 7.624618986159398;

  double v1 = -INFINITY, v2 = -INFINITY, v3 = -INFINITY;
  int i1 = LQ, i2 = LQ, i3 = LQ;

  for (int j = 0; j < 32; ++j) {
    int i = j * 64 + lane;
    const double* p0 = lt + ((size_t)bh * LQ + i) * 2;
    const double* p1 = lt + ((size_t)(64 + bh) * LQ + i) * 2;
    double l = p0[0] + p1[0];
    double tt = p0[1] + p1[1];
    double v = 0.125 * (tt / l) - log(l) + logL;
    vals[i] = v;
    lsh[i] = (float)l;               // softmax denominator for this row
    if (v > v1)      { v3 = v2; i3 = i2; v2 = v1; i2 = i1; v1 = v; i1 = i; }
    else if (v > v2) { v3 = v2; i3 = i2; v2 = v;  i2 = i; }
    else if (v > v3) { v3 = v;  i3 = i; }
  }

  for (int u = 0; u < UU; ++u) {
    if (i1 == LQ) {
      v1 = v2 = v3 = -INFINITY;
      i1 = i2 = i3 = LQ;
      for (int j = 0; j < 32; ++j) {
        int i = j * 64 + lane;
        double v = vals[i];
        if (v > v1)      { v3 = v2; i3 = i2; v2 = v1; i2 = i1; v1 = v; i1 = i; }
        else if (v > v2) { v3 = v2; i3 = i2; v2 = v;  i2 = i; }
        else if (v > v3) { v3 = v;  i3 = i; }
      }
    }

    double gv = v1;
    int gi = i1;
#pragma unroll
    for (int m = 1; m < 64; m <<= 1) {
      double ov = __shfl_xor(gv, m);
      int oi = __shfl_xor(gi, m);
      if (ov > gv || (ov == gv && oi < gi)) { gv = ov; gi = oi; }
    }
    if (lane == 0) idxout[bh * UU + u] = gi;
    if ((gi & 63) == lane) {
      l3out[bh * UU + u] = lsh[gi];  // emit denominator of the winner
      vals[gi] = -INFINITY;
      v1 = v2; i1 = i2;
      v2 = v3; i2 = i3;
      v3 = -INFINITY; i3 = LQ;
    }
  }
}

// ---------------------------------------------------------------------------
// attn_w_pv: r16 state (validated) -- unnormalized e in els, wout scaled at
// write, PV end-scale + atomicAdd scatter into zeroed out.
// ---------------------------------------------------------------------------
__global__ __launch_bounds__(256) void attn_w_pv(const float* __restrict__ Q,
                                                 const _Float16* __restrict__ ksp,
                                                 const int* __restrict__ sel,
                                                 const float* __restrict__ l3,
                                                 const float* __restrict__ V,
                                                 float* __restrict__ wout,
                                                 float* __restrict__ out) {
  int bh = blockIdx.x >> 4;
  int ks = blockIdx.x & 15;
  int b = bh >> 4, h = bh & 15;
  int t = threadIdx.x;
  int lane = t & 63, w = t >> 6;
  int quad = lane >> 4, l15 = lane & 15;

  __shared__ __align__(16) _Float16 kbuf[8192];   // 16 KB chunk image
  __shared__ float els[48 * 132];                 // 25.3 KB (UNNORMALIZED e)
  __shared__ int sidx[UU];
  __shared__ float l3i[48];                       // 1/l3 (0 for pad rows)

  if (t < UU) sidx[t] = sel[bh * UU + t];
  if (t < 48) l3i[t] = (t < UU) ? 1.f / l3[bh * UU + t] : 0.f;
  __syncthreads();

  f16x8 ahi[3][2], alo[3][2];
#pragma unroll
  for (int qt = 0; qt < 3; ++qt) {
    int u = qt * 16 + l15;
    if (u > 37) u = 37;                           // duplicate row 37 for pads
    const float* qrow = Q + ((size_t)(b * LQ + sidx[u])) * DM + h * DH;
#pragma unroll
    for (int c = 0; c < 2; ++c) {
      const float* p = qrow + c * 32 + quad * 8;
      float4 x0 = *(const float4*)p;
      float4 x1 = *(const float4*)(p + 4);
      f16x8 hi, lo;
#define QCV(i, xx) { float x_ = (xx); _Float16 hh = (_Float16)x_; hi[i] = hh; lo[i] = (_Float16)(x_ - (float)hh); }
      QCV(0, x0.x) QCV(1, x0.y) QCV(2, x0.z) QCV(3, x0.w)
      QCV(4, x1.x) QCV(5, x1.y) QCV(6, x1.z) QCV(7, x1.w)
#undef QCV
      ahi[qt][c] = hi;
      alo[qt][c] = lo;
    }
  }

  int bsw0 = quad ^ (l15 & 7);
  int bsw1 = (quad + 4) ^ (l15 & 7);
  const float C1 = 0.18033688011112042f;
  const char* gch = (const char*)(ksp + ((size_t)(bh * 32 + ks * 2)) * 8192);
  _Float16* khi = kbuf;
  _Float16* klo = kbuf + 4096;

  for (int chunk = 0; chunk < 2; ++chunk) {
    __syncthreads();
    {
      const char* gs = gch + (size_t)chunk * 16384 + (size_t)t * 16;
      char* ls = (char*)kbuf + (size_t)(w * 64) * 16;
#pragma unroll
      for (int i = 0; i < 4; ++i)
        GL2LDS16(gs + i * 4096, ls + i * 4096);
    }
    __syncthreads();
    int key = w * 16 + l15;
    f16x8 bhi0 = *(const f16x8*)(khi + key * 64 + bsw0 * 8);
    f16x8 bhi1 = *(const f16x8*)(khi + key * 64 + bsw1 * 8);
    f16x8 blo0 = *(const f16x8*)(klo + key * 64 + bsw0 * 8);
    f16x8 blo1 = *(const f16x8*)(klo + key * 64 + bsw1 * 8);
#pragma unroll
    for (int qt = 0; qt < 3; ++qt) {
      f32x4 cacc = {0.f, 0.f, 0.f, 0.f};
      cacc = __builtin_amdgcn_mfma_f32_16x16x32_f16(alo[qt][0], bhi0, cacc, 0, 0, 0);
      cacc = __builtin_amdgcn_mfma_f32_16x16x32_f16(alo[qt][1], bhi1, cacc, 0, 0, 0);
      cacc = __builtin_amdgcn_mfma_f32_16x16x32_f16(ahi[qt][0], blo0, cacc, 0, 0, 0);
      cacc = __builtin_amdgcn_mfma_f32_16x16x32_f16(ahi[qt][1], blo1, cacc, 0, 0, 0);
      cacc = __builtin_amdgcn_mfma_f32_16x16x32_f16(ahi[qt][0], bhi0, cacc, 0, 0, 0);
      cacc = __builtin_amdgcn_mfma_f32_16x16x32_f16(ahi[qt][1], bhi1, cacc, 0, 0, 0);
#pragma unroll
      for (int r = 0; r < 4; ++r) {
        int row = qt * 16 + quad * 4 + r;
        els[row * 132 + chunk * 64 + w * 16 + l15] = EXP2F(cacc[r] * C1);
      }
    }
  }
  __syncthreads();

  // coalesced wout dump -- normalized at write
  for (int i = t; i < UU * 128; i += 256) {
    int u = i >> 7, k = i & 127;
    wout[((size_t)(bh * UU + u)) * LQ + ks * 128 + k] = els[u * 132 + k] * l3i[u];
  }

  // ---- PV phase: unnormalized accumulate, one end-scale, atomic scatter ----
  int d = t & 63, ug = t >> 6;
  const float* vbase = V + ((size_t)(b * LQ + ks * 128)) * DM + h * DH + d;
  float o[10];
#pragma unroll
  for (int p = 0; p < 10; ++p) o[p] = 0.f;

  for (int j4 = 0; j4 < 128; j4 += 4) {
    float v0 = vbase[(size_t)(j4 + 0) * DM];
    float v1 = vbase[(size_t)(j4 + 1) * DM];
    float v2 = vbase[(size_t)(j4 + 2) * DM];
    float v3 = vbase[(size_t)(j4 + 3) * DM];
#pragma unroll
    for (int p = 0; p < 10; ++p) {
      float4 pw = *(const float4*)(els + (ug + 4 * p) * 132 + j4);
      o[p] = fmaf(pw.x, v0, o[p]);
      o[p] = fmaf(pw.y, v1, o[p]);
      o[p] = fmaf(pw.z, v2, o[p]);
      o[p] = fmaf(pw.w, v3, o[p]);
    }
  }

#pragma unroll
  for (int p = 0; p < 10; ++p) {
    int u = ug + 4 * p;
    if (u < UU) {
      float* dst = out + ((size_t)(b * LQ + sidx[u])) * DM + h * DH + d;
      atomicAdd(dst, o[p] * l3i[u]);
    }
  }
}

extern "C" void kernel_launch(void* const* d_in, const int* in_sizes, int n_in,
                              void* d_out, int out_size, void* d_ws, size_t ws_size,
                              hipStream_t stream) {
  (void)in_sizes; (void)n_in;
  if (ws_size < F_NEED) return;   // fail visibly (poisoned out) over UB
  const float* Q = (const float*)d_in[0];
  const float* K = (const float*)d_in[1];
  const float* V = (const float*)d_in[2];
  float* out = (float*)d_out;
  float* wout = out + (size_t)4 * LQ * DM;
  char* ws = (char*)d_ws;

  double* lt = (double*)ws;
  int* sel = (int*)(ws + F_OFF_SEL);
  float* l3 = (float*)(ws + F_OFF_L3);
  _Float16* ksp = (_Float16*)(ws + F_OFF_KSP);

  ksplit_kernel<<<4096, 256, 0, stream>>>(K, ksp, out);
  kl_mfma2<<<2048, 256, 0, stream>>>(Q, ksp, lt);
  topk2<<<NBH, 64, 0, stream>>>(lt, sel, l3);
  attn_w_pv<<<NBH * 16, 256, 0, stream>>>(Q, ksp, sel, l3, V, wout, out);
}

// Round 9
// 328.420 us; speedup vs baseline: 1.0504x; 1.0381x over previous
//
#include <hip/hip_runtime.h>
#include <math.h>

#define LQ 2048
#define DM 1024
#define NH 16
#define DH 64
#define UU 38
#define NBH 64            // B*NH = 4*16
#define SCALE 0.125f      // 1/sqrt(64)

typedef _Float16 f16x8 __attribute__((ext_vector_type(8)));
typedef float f32x4 __attribute__((ext_vector_type(4)));
typedef float f32x2 __attribute__((ext_vector_type(2)));

#if __has_builtin(__builtin_amdgcn_exp2f)
#define EXP2F(x) __builtin_amdgcn_exp2f(x)
#else
#define EXP2F(x) exp2f(x)
#endif

// async global->LDS DMA, 16B per lane. LDS dest is wave-uniform base + lane*16.
#define GL2LDS16(gp, lp)                                           \
  __builtin_amdgcn_global_load_lds(                                \
      (const __attribute__((address_space(1))) void*)(gp),         \
      (__attribute__((address_space(3))) void*)(lp), 16, 0, 0)

// ---- workspace layout (bytes), total 40,700,928 ----
//   lt    : [64][2048] double2 {v, l}      [0, 2097152)  (r18: halved, final
//           KL value + softmax denominator, computed in kl's epilogue)
//   sel   : 64*38 int                       +4194304 (offset unchanged)
//   l3    : 64*38 f32 (f64-accurate softmax denominators, from topk2)
//   ksp   : [64][32][8192] f16 @ 7146496    (33,554,432 B)
#define F_OFF_SEL   4194304
#define F_OFF_L3    4204032
#define F_OFF_KSP   7146496
#define F_NEED      40700928ull

// ---------------------------------------------------------------------------
// ksplit: K fp32 -> fp16 hi/lo split + dense-output zero fill. Unchanged
// (validated r16).
// ---------------------------------------------------------------------------
__global__ __launch_bounds__(256) void ksplit_kernel(const float* __restrict__ K,
                                                     _Float16* __restrict__ ksp,
                                                     float* __restrict__ outz) {
  int idx = blockIdx.x * 256 + threadIdx.x;   // 1,048,576 total
  int p = idx & 7;
  int k = (idx >> 3) & 63;
  int kc = (idx >> 9) & 31;
  int bh = idx >> 14;
  int b = bh >> 4, h = bh & 15;
  const float* src = K + ((size_t)(b * LQ + kc * 64 + k)) * DM + h * DH + (p ^ (k & 7)) * 8;
  float4 x0 = *(const float4*)src;
  float4 x1 = *(const float4*)(src + 4);
  f16x8 hi, lo;
#define KCV(i, xx) { float x_ = (xx); _Float16 hh = (_Float16)x_; hi[i] = hh; lo[i] = (_Float16)(x_ - (float)hh); }
  KCV(0, x0.x) KCV(1, x0.y) KCV(2, x0.z) KCV(3, x0.w)
  KCV(4, x1.x) KCV(5, x1.y) KCV(6, x1.z) KCV(7, x1.w)
#undef KCV
  _Float16* base = ksp + ((size_t)(bh * 32 + kc)) * 8192;
  *(f16x8*)(base + k * 64 + p * 8) = hi;
  *(f16x8*)(base + 4096 + k * 64 + p * 8) = lo;

  float4 z = {0.f, 0.f, 0.f, 0.f};
  *(float4*)(outz + (size_t)idx * 8) = z;
  *(float4*)(outz + (size_t)idx * 8 + 4) = z;
}

// ---------------------------------------------------------------------------
// kl_mfma2 r18: sp-split MERGED (grid 1024 = 64 bh x 16 qc; 64 sub-chunks
// per block over the full 2048 keys). Same counted-vmcnt 3-buffer ring as
// r17 (validated), same fold cadence (every 64 keys), same math. Epilogue
// now computes the FINAL KL value v = 0.125*(t/l) - log(l) + logL in f64
// (identical formula/op order as topk2 had) and writes double2 {v, l}:
// Q read once (was 2x), lt 4MB -> 2MB, topk2's f64 adds + 2048 logs gone.
// Concurrency: 4 blocks/CU dispatched, LDS cap 6, VGPR ~68 -> all resident.
// ---------------------------------------------------------------------------
__global__ __launch_bounds__(256) void kl_mfma2(const float* __restrict__ Q,
                                                const _Float16* __restrict__ ksp,
                                                double* __restrict__ lt) {
  int bh = blockIdx.x & 63;
  int qc = blockIdx.x >> 6;           // 0..15
  int b = bh >> 4, h = bh & 15;
  int t = threadIdx.x;
  int lane = t & 63, w = t >> 6;
  int quad = lane >> 4, l15 = lane & 15;

  __shared__ __align__(16) _Float16 kbuf[12288];   // 24 KB = 3 x 8 KB ring

  f16x8 ahi[2][2], alo[2][2];
  {
    const float* qrow = Q + ((size_t)(b * LQ + qc * 128)) * DM + h * DH;
#pragma unroll
    for (int qt = 0; qt < 2; ++qt)
#pragma unroll
      for (int c = 0; c < 2; ++c) {
        const float* p = qrow + (size_t)(w * 32 + qt * 16 + l15) * DM + c * 32 + quad * 8;
        float4 x0 = *(const float4*)p;
        float4 x1 = *(const float4*)(p + 4);
        f16x8 hi, lo;
#define QCV(i, xx) { float x_ = (xx); _Float16 hh = (_Float16)x_; hi[i] = hh; lo[i] = (_Float16)(x_ - (float)hh); }
        QCV(0, x0.x) QCV(1, x0.y) QCV(2, x0.z) QCV(3, x0.w)
        QCV(4, x1.x) QCV(5, x1.y) QCV(6, x1.z) QCV(7, x1.w)
#undef QCV
        ahi[qt][c] = hi;
        alo[qt][c] = lo;
      }
  }

  int bsw0 = quad ^ (l15 & 7);
  int bsw1 = (quad + 4) ^ (l15 & 7);
  const float C1 = 0.18033688011112042f;  // SCALE * log2(e)

  double l64[2][4], t64[2][4];
#pragma unroll
  for (int qt = 0; qt < 2; ++qt)
#pragma unroll
    for (int r = 0; r < 4; ++r) { l64[qt][r] = 0.0; t64[qt][r] = 0.0; }

  f32x2 l32[2][2], t32[2][2];
#pragma unroll
  for (int qt = 0; qt < 2; ++qt)
#pragma unroll
    for (int rp = 0; rp < 2; ++rp) {
      l32[qt][rp] = (f32x2){0.f, 0.f};
      t32[qt][rp] = (f32x2){0.f, 0.f};
    }

  // per-lane global src base over ALL 32 chunk-pairs of this bh.
  // sub-chunk m (0..63): hi at +(m>>1)*16384+(m&1)*4096, lo at hi+8192.
  const char* gch8 = (const char*)(ksp + ((size_t)(bh * 32)) * 8192) + t * 16;
  // wave-uniform LDS dest base; buffer n: hi at +n*8192, lo at +n*8192+4096.
  char* lbb = (char*)kbuf + w * 1024;

#define STAGE(m_, n_)                                                           \
  { const char* s_ = gch8 + (((m_) >> 1) * 16384) + (((m_) & 1) * 4096);        \
    GL2LDS16(s_, lbb + (n_) * 8192);                                            \
    GL2LDS16(s_ + 8192, lbb + (n_) * 8192 + 4096); }

#define KLSTEP(N_)                                                              \
  _Pragma("unroll")                                                             \
  for (int kt = 0; kt < 2; ++kt) {                                              \
    int key = kt * 16 + l15;                                                    \
    const _Float16* KHI = kbuf + (N_) * 4096;                                   \
    const _Float16* KLO = KHI + 2048;                                           \
    f16x8 bhi0 = *(const f16x8*)(KHI + key * 64 + bsw0 * 8);                    \
    f16x8 bhi1 = *(const f16x8*)(KHI + key * 64 + bsw1 * 8);                    \
    f16x8 blo0 = *(const f16x8*)(KLO + key * 64 + bsw0 * 8);                    \
    f16x8 blo1 = *(const f16x8*)(KLO + key * 64 + bsw1 * 8);                    \
    _Pragma("unroll")                                                           \
    for (int qt = 0; qt < 2; ++qt) {                                            \
      f32x4 cacc = {0.f, 0.f, 0.f, 0.f};                                        \
      __builtin_amdgcn_s_setprio(1);                                            \
      cacc = __builtin_amdgcn_mfma_f32_16x16x32_f16(alo[qt][0], bhi0, cacc, 0, 0, 0); \
      cacc = __builtin_amdgcn_mfma_f32_16x16x32_f16(alo[qt][1], bhi1, cacc, 0, 0, 0); \
      cacc = __builtin_amdgcn_mfma_f32_16x16x32_f16(ahi[qt][0], blo0, cacc, 0, 0, 0); \
      cacc = __builtin_amdgcn_mfma_f32_16x16x32_f16(ahi[qt][1], blo1, cacc, 0, 0, 0); \
      cacc = __builtin_amdgcn_mfma_f32_16x16x32_f16(ahi[qt][0], bhi0, cacc, 0, 0, 0); \
      cacc = __builtin_amdgcn_mfma_f32_16x16x32_f16(ahi[qt][1], bhi1, cacc, 0, 0, 0); \
      __builtin_amdgcn_s_setprio(0);                                            \
      _Pragma("unroll")                                                         \
      for (int rp = 0; rp < 2; ++rp) {                                          \
        f32x2 rr = { cacc[2 * rp], cacc[2 * rp + 1] };                          \
        f32x2 sc = rr * C1;                                                     \
        f32x2 e  = { EXP2F(sc[0]), EXP2F(sc[1]) };                              \
        l32[qt][rp] += e;                                                       \
        t32[qt][rp] += rr * e;                                                  \
      }                                                                         \
    }                                                                           \
  }

#define FOLD()                                                                  \
  { _Pragma("unroll")                                                           \
    for (int qt = 0; qt < 2; ++qt)                                              \
      _Pragma("unroll")                                                         \
      for (int rp = 0; rp < 2; ++rp)                                            \
        _Pragma("unroll")                                                       \
        for (int c = 0; c < 2; ++c) {                                           \
          l64[qt][rp * 2 + c] += (double)l32[qt][rp][c];                        \
          t64[qt][rp * 2 + c] += (double)t32[qt][rp][c];                        \
          l32[qt][rp][c] = 0.f;                                                 \
          t32[qt][rp][c] = 0.f;                                                 \
        } }

  // wait own stage (1 stage = 2 loads stays in flight), barrier, then issue
  // next stage + compute. sched_barrier pins the wait (rule #18).
#define SUB2(vm_)                                                               \
  asm volatile("s_waitcnt vmcnt(" vm_ ")" ::: "memory");                        \
  __builtin_amdgcn_sched_barrier(0);                                            \
  __builtin_amdgcn_s_barrier();

  // prologue: stage sub-chunks 0,1 into buffers 0,1
  STAGE(0, 0)
  STAGE(1, 1)

  for (int k5 = 0; k5 < 10; ++k5) {
    int i0 = 6 * k5;
    SUB2("2") STAGE(i0 + 2, 2) KLSTEP(0)
    SUB2("2") STAGE(i0 + 3, 0) KLSTEP(1) FOLD()
    SUB2("2") STAGE(i0 + 4, 1) KLSTEP(2)
    SUB2("2") STAGE(i0 + 5, 2) KLSTEP(0) FOLD()
    SUB2("2") STAGE(i0 + 6, 0) KLSTEP(1)
    SUB2("2") STAGE(i0 + 7, 1) KLSTEP(2) FOLD()
  }
  // epilogue: i = 60..63 (buffers 0,1,2,0; stages 62,63 issued here)
  SUB2("2") STAGE(62, 2) KLSTEP(0)
  SUB2("2") STAGE(63, 0) KLSTEP(1) FOLD()
  SUB2("2") KLSTEP(2)
  SUB2("0") KLSTEP(0) FOLD()

#undef SUB2
#undef STAGE
#undef KLSTEP
#undef FOLD

  const double logL = 7.624618986159398;
#pragma unroll
  for (int qt = 0; qt < 2; ++qt)
#pragma unroll
    for (int r = 0; r < 4; ++r) {
      double lv = l64[qt][r], tv = t64[qt][r];
#pragma unroll
      for (int m = 1; m < 16; m <<= 1) {
        lv += __shfl_xor(lv, m);
        tv += __shfl_xor(tv, m);
      }
      if (l15 == 0) {
        int qg = qc * 128 + w * 32 + qt * 16 + quad * 4 + r;
        // final KL value (identical formula/op order as old topk2)
        double v = 0.125 * (tv / lv) - log(lv) + logL;
        double* dst = lt + ((size_t)bh * LQ + qg) * 2;
        dst[0] = v;
        dst[1] = lv;
      }
    }
}

// ---------------------------------------------------------------------------
// topk2 r18: scan is now a pure double2 load (v, l precomputed by kl).
// Register top-3 selection unchanged (validated r13-r17).
// ---------------------------------------------------------------------------
__global__ __launch_bounds__(64) void topk2(const double* __restrict__ lt,
                                            int* __restrict__ idxout,
                                            float* __restrict__ l3out) {
  int bh = blockIdx.x;
  int lane = threadIdx.x;
  __shared__ double vals[LQ];
  __shared__ float lsh[LQ];

  double v1 = -INFINITY, v2 = -INFINITY, v3 = -INFINITY;
  int i1 = LQ, i2 = LQ, i3 = LQ;

  for (int j = 0; j < 32; ++j) {
    int i = j * 64 + lane;
    const double* p = lt + ((size_t)bh * LQ + i) * 2;
    double v = p[0];
    vals[i] = v;
    lsh[i] = (float)p[1];            // softmax denominator for this row
    if (v > v1)      { v3 = v2; i3 = i2; v2 = v1; i2 = i1; v1 = v; i1 = i; }
    else if (v > v2) { v3 = v2; i3 = i2; v2 = v;  i2 = i; }
    else if (v > v3) { v3 = v;  i3 = i; }
  }

  for (int u = 0; u < UU; ++u) {
    if (i1 == LQ) {
      v1 = v2 = v3 = -INFINITY;
      i1 = i2 = i3 = LQ;
      for (int j = 0; j < 32; ++j) {
        int i = j * 64 + lane;
        double v = vals[i];
        if (v > v1)      { v3 = v2; i3 = i2; v2 = v1; i2 = i1; v1 = v; i1 = i; }
        else if (v > v2) { v3 = v2; i3 = i2; v2 = v;  i2 = i; }
        else if (v > v3) { v3 = v;  i3 = i; }
      }
    }

    double gv = v1;
    int gi = i1;
#pragma unroll
    for (int m = 1; m < 64; m <<= 1) {
      double ov = __shfl_xor(gv, m);
      int oi = __shfl_xor(gi, m);
      if (ov > gv || (ov == gv && oi < gi)) { gv = ov; gi = oi; }
    }
    if (lane == 0) idxout[bh * UU + u] = gi;
    if ((gi & 63) == lane) {
      l3out[bh * UU + u] = lsh[gi];  // emit denominator of the winner
      vals[gi] = -INFINITY;
      v1 = v2; i1 = i2;
      v2 = v3; i2 = i3;
      v3 = -INFINITY; i3 = LQ;
    }
  }
}

// ---------------------------------------------------------------------------
// attn_w_pv: r16 state (validated) -- unnormalized e in els, wout scaled at
// write, PV end-scale + atomicAdd scatter into zeroed out.
// ---------------------------------------------------------------------------
__global__ __launch_bounds__(256) void attn_w_pv(const float* __restrict__ Q,
                                                 const _Float16* __restrict__ ksp,
                                                 const int* __restrict__ sel,
                                                 const float* __restrict__ l3,
                                                 const float* __restrict__ V,
                                                 float* __restrict__ wout,
                                                 float* __restrict__ out) {
  int bh = blockIdx.x >> 4;
  int ks = blockIdx.x & 15;
  int b = bh >> 4, h = bh & 15;
  int t = threadIdx.x;
  int lane = t & 63, w = t >> 6;
  int quad = lane >> 4, l15 = lane & 15;

  __shared__ __align__(16) _Float16 kbuf[8192];   // 16 KB chunk image
  __shared__ float els[48 * 132];                 // 25.3 KB (UNNORMALIZED e)
  __shared__ int sidx[UU];
  __shared__ float l3i[48];                       // 1/l3 (0 for pad rows)

  if (t < UU) sidx[t] = sel[bh * UU + t];
  if (t < 48) l3i[t] = (t < UU) ? 1.f / l3[bh * UU + t] : 0.f;
  __syncthreads();

  f16x8 ahi[3][2], alo[3][2];
#pragma unroll
  for (int qt = 0; qt < 3; ++qt) {
    int u = qt * 16 + l15;
    if (u > 37) u = 37;                           // duplicate row 37 for pads
    const float* qrow = Q + ((size_t)(b * LQ + sidx[u])) * DM + h * DH;
#pragma unroll
    for (int c = 0; c < 2; ++c) {
      const float* p = qrow + c * 32 + quad * 8;
      float4 x0 = *(const float4*)p;
      float4 x1 = *(const float4*)(p + 4);
      f16x8 hi, lo;
#define QCV(i, xx) { float x_ = (xx); _Float16 hh = (_Float16)x_; hi[i] = hh; lo[i] = (_Float16)(x_ - (float)hh); }
      QCV(0, x0.x) QCV(1, x0.y) QCV(2, x0.z) QCV(3, x0.w)
      QCV(4, x1.x) QCV(5, x1.y) QCV(6, x1.z) QCV(7, x1.w)
#undef QCV
      ahi[qt][c] = hi;
      alo[qt][c] = lo;
    }
  }

  int bsw0 = quad ^ (l15 & 7);
  int bsw1 = (quad + 4) ^ (l15 & 7);
  const float C1 = 0.18033688011112042f;
  const char* gch = (const char*)(ksp + ((size_t)(bh * 32 + ks * 2)) * 8192);
  _Float16* khi = kbuf;
  _Float16* klo = kbuf + 4096;

  for (int chunk = 0; chunk < 2; ++chunk) {
    __syncthreads();
    {
      const char* gs = gch + (size_t)chunk * 16384 + (size_t)t * 16;
      char* ls = (char*)kbuf + (size_t)(w * 64) * 16;
#pragma unroll
      for (int i = 0; i < 4; ++i)
        GL2LDS16(gs + i * 4096, ls + i * 4096);
    }
    __syncthreads();
    int key = w * 16 + l15;
    f16x8 bhi0 = *(const f16x8*)(khi + key * 64 + bsw0 * 8);
    f16x8 bhi1 = *(const f16x8*)(khi + key * 64 + bsw1 * 8);
    f16x8 blo0 = *(const f16x8*)(klo + key * 64 + bsw0 * 8);
    f16x8 blo1 = *(const f16x8*)(klo + key * 64 + bsw1 * 8);
#pragma unroll
    for (int qt = 0; qt < 3; ++qt) {
      f32x4 cacc = {0.f, 0.f, 0.f, 0.f};
      cacc = __builtin_amdgcn_mfma_f32_16x16x32_f16(alo[qt][0], bhi0, cacc, 0, 0, 0);
      cacc = __builtin_amdgcn_mfma_f32_16x16x32_f16(alo[qt][1], bhi1, cacc, 0, 0, 0);
      cacc = __builtin_amdgcn_mfma_f32_16x16x32_f16(ahi[qt][0], blo0, cacc, 0, 0, 0);
      cacc = __builtin_amdgcn_mfma_f32_16x16x32_f16(ahi[qt][1], blo1, cacc, 0, 0, 0);
      cacc = __builtin_amdgcn_mfma_f32_16x16x32_f16(ahi[qt][0], bhi0, cacc, 0, 0, 0);
      cacc = __builtin_amdgcn_mfma_f32_16x16x32_f16(ahi[qt][1], bhi1, cacc, 0, 0, 0);
#pragma unroll
      for (int r = 0; r < 4; ++r) {
        int row = qt * 16 + quad * 4 + r;
        els[row * 132 + chunk * 64 + w * 16 + l15] = EXP2F(cacc[r] * C1);
      }
    }
  }
  __syncthreads();

  // coalesced wout dump -- normalized at write
  for (int i = t; i < UU * 128; i += 256) {
    int u = i >> 7, k = i & 127;
    wout[((size_t)(bh * UU + u)) * LQ + ks * 128 + k] = els[u * 132 + k] * l3i[u];
  }

  // ---- PV phase: unnormalized accumulate, one end-scale, atomic scatter ----
  int d = t & 63, ug = t >> 6;
  const float* vbase = V + ((size_t)(b * LQ + ks * 128)) * DM + h * DH + d;
  float o[10];
#pragma unroll
  for (int p = 0; p < 10; ++p) o[p] = 0.f;

  for (int j4 = 0; j4 < 128; j4 += 4) {
    float v0 = vbase[(size_t)(j4 + 0) * DM];
    float v1 = vbase[(size_t)(j4 + 1) * DM];
    float v2 = vbase[(size_t)(j4 + 2) * DM];
    float v3 = vbase[(size_t)(j4 + 3) * DM];
#pragma unroll
    for (int p = 0; p < 10; ++p) {
      float4 pw = *(const float4*)(els + (ug + 4 * p) * 132 + j4);
      o[p] = fmaf(pw.x, v0, o[p]);
      o[p] = fmaf(pw.y, v1, o[p]);
      o[p] = fmaf(pw.z, v2, o[p]);
      o[p] = fmaf(pw.w, v3, o[p]);
    }
  }

#pragma unroll
  for (int p = 0; p < 10; ++p) {
    int u = ug + 4 * p;
    if (u < UU) {
      float* dst = out + ((size_t)(b * LQ + sidx[u])) * DM + h * DH + d;
      atomicAdd(dst, o[p] * l3i[u]);
    }
  }
}

extern "C" void kernel_launch(void* const* d_in, const int* in_sizes, int n_in,
                              void* d_out, int out_size, void* d_ws, size_t ws_size,
                              hipStream_t stream) {
  (void)in_sizes; (void)n_in;
  if (ws_size < F_NEED) return;   // fail visibly (poisoned out) over UB
  const float* Q = (const float*)d_in[0];
  const float* K = (const float*)d_in[1];
  const float* V = (const float*)d_in[2];
  float* out = (float*)d_out;
  float* wout = out + (size_t)4 * LQ * DM;
  char* ws = (char*)d_ws;

  double* lt = (double*)ws;
  int* sel = (int*)(ws + F_OFF_SEL);
  float* l3 = (float*)(ws + F_OFF_L3);
  _Float16* ksp = (_Float16*)(ws + F_OFF_KSP);

  ksplit_kernel<<<4096, 256, 0, stream>>>(K, ksp, out);
  kl_mfma2<<<1024, 256, 0, stream>>>(Q, ksp, lt);
  topk2<<<NBH, 64, 0, stream>>>(lt, sel, l3);
  attn_w_pv<<<NBH * 16, 256, 0, stream>>>(Q, ksp, sel, l3, V, wout, out);
}